// Round 1
// baseline (686.197 us; speedup 1.0000x reference)
//
#include <hip/hip_runtime.h>
#include <hip/hip_bf16.h>

// OrdinalRegressionLoss: B x 256 float32 logits, int targets.
// per_elem(k) = softplus( (k<t) ? cum_k : -cum_k ), k=0..254; out = mean over rows of row-sums.
// One wave per row; lane i float4-loads cols 4i..4i+3 (coalesced 1KiB/row/wave).
// Wave shfl_up scan for cumsum; double partials -> stage-2 reduce. Memory-bound (~512MiB read).

#define WAVE 64
#define BLOCK 256
#define WAVES_PER_BLOCK (BLOCK / WAVE)
#define NBLOCKS 8192
#define NCLASS 256

__device__ __forceinline__ float softplus_f(float z) {
    // softplus(z) = max(z,0) + log(1 + exp(-|z|)); hw exp/log, accurate enough vs threshold
    float az = fabsf(z);
    float e  = __expf(-az);
    return fmaxf(z, 0.0f) + __logf(1.0f + e);
}

__global__ __launch_bounds__(BLOCK) void ordloss_main(
        const float* __restrict__ logits,
        const int*   __restrict__ targets,
        double*      __restrict__ partials,
        int B, int rows_per_wave) {
    const int lane = threadIdx.x & (WAVE - 1);
    const int wib  = threadIdx.x >> 6;               // wave index in block
    const long long waveGlobal = (long long)blockIdx.x * WAVES_PER_BLOCK + wib;
    const long long rowBase = waveGlobal * rows_per_wave;

    double acc = 0.0;  // per-lane accumulator across rows

    for (int i = 0; i < rows_per_wave; ++i) {
        long long row = rowBase + i;
        if (row >= B) break;

        // coalesced: lane i reads 16B at row*1024 + 16*i
        const float4 v = reinterpret_cast<const float4*>(logits + row * NCLASS)[lane];
        const int t = targets[row];  // wave-uniform -> scalar load/broadcast

        // local inclusive prefix within the 4 elements
        float l0 = v.x;
        float l1 = l0 + v.y;
        float l2 = l1 + v.z;
        float l3 = l2 + v.w;
        const float tot = l3;

        // wave-wide inclusive scan of lane totals (6 shfl_up steps)
        float sc = tot;
        #pragma unroll
        for (int off = 1; off < WAVE; off <<= 1) {
            float y = __shfl_up(sc, off, WAVE);
            if (lane >= off) sc += y;
        }
        const float excl = sc - tot;   // exclusive prefix of this lane's chunk

        const float c0 = excl + l0;
        const float c1 = excl + l1;
        const float c2 = excl + l2;
        const float c3 = excl + l3;

        const int k0 = lane << 2;
        float lsum;
        lsum  = softplus_f((k0 + 0 < t) ? c0 : -c0);
        lsum += softplus_f((k0 + 1 < t) ? c1 : -c1);
        lsum += softplus_f((k0 + 2 < t) ? c2 : -c2);
        if (lane < WAVE - 1)                              // k = 255 excluded (only lane 63 j=3)
            lsum += softplus_f((k0 + 3 < t) ? c3 : -c3);

        acc += (double)lsum;
    }

    // wave reduce (double)
    #pragma unroll
    for (int off = 32; off > 0; off >>= 1)
        acc += __shfl_down(acc, off, WAVE);

    __shared__ double sdata[WAVES_PER_BLOCK];
    if (lane == 0) sdata[wib] = acc;
    __syncthreads();
    if (threadIdx.x == 0) {
        double s = 0.0;
        #pragma unroll
        for (int w = 0; w < WAVES_PER_BLOCK; ++w) s += sdata[w];
        partials[blockIdx.x] = s;
    }
}

__global__ __launch_bounds__(256) void ordloss_reduce(
        const double* __restrict__ partials, int n,
        float* __restrict__ out, double invB) {
    __shared__ double smem[256];
    double s = 0.0;
    for (int i = threadIdx.x; i < n; i += 256) s += partials[i];
    smem[threadIdx.x] = s;
    __syncthreads();
    for (int st = 128; st > 0; st >>= 1) {
        if (threadIdx.x < st) smem[threadIdx.x] += smem[threadIdx.x + st];
        __syncthreads();
    }
    if (threadIdx.x == 0) out[0] = (float)(smem[0] * invB);
}

extern "C" void kernel_launch(void* const* d_in, const int* in_sizes, int n_in,
                              void* d_out, int out_size, void* d_ws, size_t ws_size,
                              hipStream_t stream) {
    const float* logits  = (const float*)d_in[0];
    const int*   targets = (const int*)d_in[1];
    float*       out     = (float*)d_out;
    double*      partials = (double*)d_ws;   // NBLOCKS * 8 = 64 KiB

    const int B = in_sizes[1];
    const int total_waves = NBLOCKS * WAVES_PER_BLOCK;
    const int rows_per_wave = (B + total_waves - 1) / total_waves;

    ordloss_main<<<NBLOCKS, BLOCK, 0, stream>>>(logits, targets, partials, B, rows_per_wave);
    ordloss_reduce<<<1, 256, 0, stream>>>(partials, NBLOCKS, out, 1.0 / (double)B);
}